// Round 3
// baseline (155.983 us; speedup 1.0000x reference)
//
#include <hip/hip_runtime.h>
#include <math.h>

#define NCLS 1000
#define TPB  256      // 4 waves; threads 0..249 each own one float4 (4 elems)
#define NF4  (NCLS/4) // 250

// ---------------------------------------------------------------------------
// cum[i] for the uniform row per jax.lax.associative_scan (tree) order.
// For constant x = 0.001f, pair combines are exact doublings (x+x = 2x),
// so the scan value for prefix-count k is: sum of x*2^l over the set bits
// of k, accumulated MSB -> LSB, each add rounded in f32.
// asm barrier per step forbids any compiler reassociation/contraction.
// ---------------------------------------------------------------------------
__device__ __forceinline__ float scan_val(int k) {
    const unsigned xb = __float_as_uint(0.001f);
    const int hb = 31 - __clz(k);
    float acc = __uint_as_float(xb + ((unsigned)hb << 23));  // x * 2^hb, exact
    #pragma unroll 1
    for (int l = hb - 1; l >= 0; --l) {
        if (k & (1u << l)) {
            const float t = __uint_as_float(xb + ((unsigned)l << 23)); // x*2^l
            acc += t;
            asm volatile("" : "+v"(acc));
        }
    }
    return acc;
}

// ---------------------------------------------------------------------------
// Block reduction helpers (wave64 shfl + 4-partial LDS combine, broadcast).
// ---------------------------------------------------------------------------
__device__ __forceinline__ float block_max_f(float v, float* lds, int tid) {
    #pragma unroll
    for (int o = 32; o; o >>= 1) v = fmaxf(v, __shfl_xor(v, o));
    if ((tid & 63) == 0) lds[tid >> 6] = v;
    __syncthreads();
    v = fmaxf(fmaxf(lds[0], lds[1]), fmaxf(lds[2], lds[3]));
    __syncthreads();
    return v;
}

__device__ __forceinline__ float block_sum_f(float v, float* lds, int tid) {
    #pragma unroll
    for (int o = 32; o; o >>= 1) v += __shfl_xor(v, o);
    if ((tid & 63) == 0) lds[tid >> 6] = v;
    __syncthreads();
    v = (lds[0] + lds[1]) + (lds[2] + lds[3]);
    __syncthreads();
    return v;
}

__device__ __forceinline__ int block_sum_i(int v, int* lds, int tid) {
    #pragma unroll
    for (int o = 32; o; o >>= 1) v += __shfl_xor(v, o);
    if ((tid & 63) == 0) lds[tid >> 6] = v;
    __syncthreads();
    v = lds[0] + lds[1] + lds[2] + lds[3];
    __syncthreads();
    return v;
}

// ---------------------------------------------------------------------------
// One block per row.
// ---------------------------------------------------------------------------
__global__ __launch_bounds__(TPB) void defence_kernel(
    const float* __restrict__ logits,
    const float* __restrict__ noise,
    const float* __restrict__ u,
    float* __restrict__ out)
{
    const int row = blockIdx.x;
    const int tid = threadIdx.x;
    const bool act = tid < NF4;

    __shared__ float redf[4];
    __shared__ int   redi[4];
    __shared__ int   i_bcast;
    __shared__ unsigned char kbuf[NCLS];

    const float4* lg4 = reinterpret_cast<const float4*>(logits + (size_t)row * NCLS);
    const float4* nz4 = reinterpret_cast<const float4*>(noise  + (size_t)row * NCLS);

    // Layer 2: raw = logits / 6.0
    float raw[4] = {0.f, 0.f, 0.f, 0.f};
    if (act) {
        float4 lv = lg4[tid];
        raw[0] = lv.x / 6.0f; raw[1] = lv.y / 6.0f;
        raw[2] = lv.z / 6.0f; raw[3] = lv.w / 6.0f;
    }

    // softmax #1 -> max_conf = 1/sum(exp(raw - max))
    float mloc = act ? fmaxf(fmaxf(raw[0], raw[1]), fmaxf(raw[2], raw[3])) : -INFINITY;
    const float m1 = block_max_f(mloc, redf, tid);
    float se1 = 0.f;
    if (act)
        se1 = expf(raw[0] - m1) + expf(raw[1] - m1) + expf(raw[2] - m1) + expf(raw[3] - m1);
    const float s1 = block_sum_f(se1, redf, tid);
    const float mc = 1.0f / s1;
    const float sd = 0.3f + 0.6f * (mc * mc);

    // Layer 3: noisy = raw + noise * std
    float ny[4] = {0.f, 0.f, 0.f, 0.f};
    if (act) {
        float4 nv = nz4[tid];
        ny[0] = raw[0] + nv.x * sd; ny[1] = raw[1] + nv.y * sd;
        ny[2] = raw[2] + nv.z * sd; ny[3] = raw[3] + nv.w * sd;
    }

    // softmax #2, clip 0.6, renormalize, round to nearest 0.1 (half-even)
    mloc = act ? fmaxf(fmaxf(ny[0], ny[1]), fmaxf(ny[2], ny[3])) : -INFINITY;
    const float m2 = block_max_f(mloc, redf, tid);
    float e[4] = {0.f, 0.f, 0.f, 0.f};
    float se2 = 0.f;
    if (act) {
        e[0] = expf(ny[0] - m2); e[1] = expf(ny[1] - m2);
        e[2] = expf(ny[2] - m2); e[3] = expf(ny[3] - m2);
        se2 = (e[0] + e[1]) + (e[2] + e[3]);
    }
    const float s2 = block_sum_f(se2, redf, tid);
    float cl[4] = {0.f, 0.f, 0.f, 0.f};
    float cs = 0.f;
    if (act) {
        cl[0] = fminf(e[0] / s2, 0.6f); cl[1] = fminf(e[1] / s2, 0.6f);
        cl[2] = fminf(e[2] / s2, 0.6f); cl[3] = fminf(e[3] / s2, 0.6f);
        cs = (cl[0] + cl[1]) + (cl[2] + cl[3]);
    }
    const float rsum = block_sum_f(cs, redf, tid);
    int k[4] = {0, 0, 0, 0};
    int kls = 0;
    if (act) {
        k[0] = (int)rintf((cl[0] / rsum) * 10.0f);
        k[1] = (int)rintf((cl[1] / rsum) * 10.0f);
        k[2] = (int)rintf((cl[2] / rsum) * 10.0f);
        k[3] = (int)rintf((cl[3] / rsum) * 10.0f);
        kls = k[0] + k[1] + k[2] + k[3];
    }
    const int K = block_sum_i(kls, redi, tid);

    const float uu = u[row];
    int idx;
    if (K == 0) {
        // uniform row: cum follows the associative-scan closed form.
        const float th = uu * scan_val(NCLS);   // f32 mul, as in the f32 ref
        int cnt = 0;
        if (act) {
            const int base = 4 * tid;
            cnt = (scan_val(base + 1) < th) + (scan_val(base + 2) < th)
                + (scan_val(base + 3) < th) + (scan_val(base + 4) < th);
        }
        idx = block_sum_i(cnt, redi, tid);
    } else {
        // rare path (never expected with this data): sequential f64 staircase.
        if (act) {
            kbuf[4 * tid + 0] = (unsigned char)k[0];
            kbuf[4 * tid + 1] = (unsigned char)k[1];
            kbuf[4 * tid + 2] = (unsigned char)k[2];
            kbuf[4 * tid + 3] = (unsigned char)k[3];
        }
        __syncthreads();
        if (tid == 0) {
            const double tab[11] = {0.0, 0.1, 0.2, 0.3, 0.4, 0.5,
                                    0.6, 0.7, 0.8, 0.9, 1.0};
            double c = 0.0;
            for (int i = 0; i < NCLS; ++i) c += tab[kbuf[i]];
            const double th = (double)uu * c;
            c = 0.0;
            int cnt = 0;
            for (int i = 0; i < NCLS; ++i) {
                c += tab[kbuf[i]];
                cnt += (c < th) ? 1 : 0;
            }
            i_bcast = cnt;
        }
        __syncthreads();
        idx = i_bcast;
    }

    // epilogue: log(one_hot*(1-EPS) + EPS/C)
    const float V0 = logf(1e-7f);             // EPS/C
    const float V1 = logf(0.9999f + 1e-7f);   // (1-EPS) + EPS/C
    if (act) {
        float4 ov = {V0, V0, V0, V0};
        const int base = tid * 4;
        if (idx >= base && idx < base + 4)
            (&ov.x)[idx - base] = V1;
        reinterpret_cast<float4*>(out + (size_t)row * NCLS)[tid] = ov;
    }
}

extern "C" void kernel_launch(void* const* d_in, const int* in_sizes, int n_in,
                              void* d_out, int out_size, void* d_ws, size_t ws_size,
                              hipStream_t stream) {
    const float* logits = (const float*)d_in[0];
    const float* noise  = (const float*)d_in[1];
    const float* u      = (const float*)d_in[2];
    float* out = (float*)d_out;

    const int batch = in_sizes[2];       // 32768 rows (u is [B,1])

    hipLaunchKernelGGL(defence_kernel, dim3(batch), dim3(TPB), 0, stream,
                       logits, noise, u, out);
}

// Round 4
// 98.751 us; speedup vs baseline: 1.5796x; 1.5796x over previous
//
#include <hip/hip_runtime.h>
#include <math.h>

#define NCLS 1000
#define TPB  256      // 4 waves; threads 0..249 each own one float4 (4 elems)
#define NF4  (NCLS/4) // 250

#if __has_builtin(__builtin_amdgcn_exp2f)
__device__ __forceinline__ float fast_exp2(float x) { return __builtin_amdgcn_exp2f(x); }
#else
__device__ __forceinline__ float fast_exp2(float x) { return exp2f(x); }
#endif

// ---------------------------------------------------------------------------
// cum[i] for the uniform row per jax.lax.associative_scan (tree) order.
// For constant x = 0.001f pair combines are exact doublings, so the scan
// value for prefix-count k is sum of x*2^l over set bits of k, accumulated
// MSB -> LSB, each add rounded in f32. asm barrier forbids reassociation.
// (bit-exactness of these values was verified by R3: absmax == 0.0)
// ---------------------------------------------------------------------------
__device__ __forceinline__ float scan_val(int k) {
    const unsigned xb = __float_as_uint(0.001f);
    const int hb = 31 - __clz(k);
    float acc = __uint_as_float(xb + ((unsigned)hb << 23));  // x * 2^hb, exact
    #pragma unroll 1
    for (int l = hb - 1; l >= 0; --l) {
        if (k & (1u << l)) {
            const float t = __uint_as_float(xb + ((unsigned)l << 23)); // x*2^l
            acc += t;
            asm volatile("" : "+v"(acc));
        }
    }
    return acc;
}

// Precompute table once per launch (graph-safe, deterministic).
__global__ void init_tab(float* __restrict__ T) {
    const int i = blockIdx.x * blockDim.x + threadIdx.x;
    if (i < NCLS) T[i] = scan_val(i + 1);
}

// ---------------------------------------------------------------------------
// Block reduction helpers (wave64 shfl + 4-partial LDS combine, broadcast).
// ---------------------------------------------------------------------------
__device__ __forceinline__ float block_max_f(float v, float* lds, int tid) {
    #pragma unroll
    for (int o = 32; o; o >>= 1) v = fmaxf(v, __shfl_xor(v, o));
    if ((tid & 63) == 0) lds[tid >> 6] = v;
    __syncthreads();
    v = fmaxf(fmaxf(lds[0], lds[1]), fmaxf(lds[2], lds[3]));
    __syncthreads();
    return v;
}

__device__ __forceinline__ float block_sum_f(float v, float* lds, int tid) {
    #pragma unroll
    for (int o = 32; o; o >>= 1) v += __shfl_xor(v, o);
    if ((tid & 63) == 0) lds[tid >> 6] = v;
    __syncthreads();
    v = (lds[0] + lds[1]) + (lds[2] + lds[3]);
    __syncthreads();
    return v;
}

__device__ __forceinline__ int block_sum_i(int v, int* lds, int tid) {
    #pragma unroll
    for (int o = 32; o; o >>= 1) v += __shfl_xor(v, o);
    if ((tid & 63) == 0) lds[tid >> 6] = v;
    __syncthreads();
    v = lds[0] + lds[1] + lds[2] + lds[3];
    __syncthreads();
    return v;
}

// ---------------------------------------------------------------------------
// One block per row.
// ---------------------------------------------------------------------------
__global__ __launch_bounds__(TPB) void defence_kernel(
    const float* __restrict__ logits,
    const float* __restrict__ noise,
    const float* __restrict__ u,
    const float* __restrict__ T,
    float* __restrict__ out)
{
    const int row = blockIdx.x;
    const int tid = threadIdx.x;
    const bool act = tid < NF4;

    __shared__ float redf[4];
    __shared__ int   redi[4];
    __shared__ int   i_bcast;
    __shared__ unsigned char kbuf[NCLS];

    const float4* lg4 = reinterpret_cast<const float4*>(logits + (size_t)row * NCLS);
    const float4* nz4 = reinterpret_cast<const float4*>(noise  + (size_t)row * NCLS);

    // issue both row loads up-front (overlap latency)
    float l[4] = {0.f, 0.f, 0.f, 0.f};
    float nz[4] = {0.f, 0.f, 0.f, 0.f};
    if (act) {
        float4 lv = lg4[tid];
        float4 nv = nz4[tid];
        l[0] = lv.x; l[1] = lv.y; l[2] = lv.z; l[3] = lv.w;
        nz[0] = nv.x; nz[1] = nv.y; nz[2] = nv.z; nz[3] = nv.w;
    }

    // ---- fast path (approximate; only has to decide K==0, margin ~2.5x) ----
    // softmax #1 statistics with /6 folded into exp2: exp((l-m)/6) =
    // exp2(l*K6 - m*K6), K6 = log2(e)/6.
    float mloc = act ? fmaxf(fmaxf(l[0], l[1]), fmaxf(l[2], l[3])) : -INFINITY;
    const float m1 = block_max_f(mloc, redf, tid);           // max of raw logits
    const float K6 = 0.2404491734814939f;                    // log2(e)/6
    const float b1 = m1 * K6;
    float se1 = 0.f;
    if (act)
        se1 = (fast_exp2(fmaf(l[0], K6, -b1)) + fast_exp2(fmaf(l[1], K6, -b1)))
            + (fast_exp2(fmaf(l[2], K6, -b1)) + fast_exp2(fmaf(l[3], K6, -b1)));
    const float s1 = block_sum_f(se1, redf, tid);
    const float mc = 1.0f / s1;
    const float sd = fmaf(0.6f, mc * mc, 0.3f);

    float ny[4] = {0.f, 0.f, 0.f, 0.f};
    if (act) {
        ny[0] = fmaf(nz[0], sd, l[0] * (1.0f / 6.0f));
        ny[1] = fmaf(nz[1], sd, l[1] * (1.0f / 6.0f));
        ny[2] = fmaf(nz[2], sd, l[2] * (1.0f / 6.0f));
        ny[3] = fmaf(nz[3], sd, l[3] * (1.0f / 6.0f));
    }
    mloc = act ? fmaxf(fmaxf(ny[0], ny[1]), fmaxf(ny[2], ny[3])) : -INFINITY;
    const float m2 = block_max_f(mloc, redf, tid);
    const float L2E = 1.4426950408889634f;
    const float b2 = m2 * L2E;
    float se2 = 0.f;
    if (act)
        se2 = (fast_exp2(fmaf(ny[0], L2E, -b2)) + fast_exp2(fmaf(ny[1], L2E, -b2)))
            + (fast_exp2(fmaf(ny[2], L2E, -b2)) + fast_exp2(fmaf(ny[3], L2E, -b2)));
    const float s2 = block_sum_f(se2, redf, tid);

    const float uu = u[row];
    int idx;
    // K==0  <=>  max renorm prob = 1/(s2*rsum) <= 0.05 (rint half-even).
    // s2 > 22 gives max p < 0.046 with rsum in [0.999,1.0001] and no clipping
    // (clip needs s2 < 1.667). Data: s2 >= ~50. Boundary rows -> exact path.
    if (s2 > 22.0f) {
        const float th = uu * T[NCLS - 1];       // bit-identical to R3
        int cnt = 0;
        if (act) {
            float4 tv = reinterpret_cast<const float4*>(T)[tid];
            cnt = (tv.x < th) + (tv.y < th) + (tv.z < th) + (tv.w < th);
        }
        idx = block_sum_i(cnt, redi, tid);
    } else {
        // ---- exact reference-semantics path (block-uniform, not taken for
        // this data; guards the K==0 decision boundary) ----
        float raw[4] = {0.f, 0.f, 0.f, 0.f};
        if (act) {
            raw[0] = l[0] / 6.0f; raw[1] = l[1] / 6.0f;
            raw[2] = l[2] / 6.0f; raw[3] = l[3] / 6.0f;
        }
        const float m1x = m1 / 6.0f;             // max(raw): rounding is monotone
        float se1x = 0.f;
        if (act)
            se1x = expf(raw[0] - m1x) + expf(raw[1] - m1x)
                 + expf(raw[2] - m1x) + expf(raw[3] - m1x);
        const float s1x = block_sum_f(se1x, redf, tid);
        const float mcx = 1.0f / s1x;
        const float sdx = 0.3f + 0.6f * (mcx * mcx);
        float nyx[4] = {0.f, 0.f, 0.f, 0.f};
        if (act) {
            nyx[0] = raw[0] + nz[0] * sdx; nyx[1] = raw[1] + nz[1] * sdx;
            nyx[2] = raw[2] + nz[2] * sdx; nyx[3] = raw[3] + nz[3] * sdx;
        }
        float mlx = act ? fmaxf(fmaxf(nyx[0], nyx[1]), fmaxf(nyx[2], nyx[3]))
                        : -INFINITY;
        const float m2x = block_max_f(mlx, redf, tid);
        float e[4] = {0.f, 0.f, 0.f, 0.f};
        float se2x = 0.f;
        if (act) {
            e[0] = expf(nyx[0] - m2x); e[1] = expf(nyx[1] - m2x);
            e[2] = expf(nyx[2] - m2x); e[3] = expf(nyx[3] - m2x);
            se2x = (e[0] + e[1]) + (e[2] + e[3]);
        }
        const float s2x = block_sum_f(se2x, redf, tid);
        float cl[4] = {0.f, 0.f, 0.f, 0.f};
        float cs = 0.f;
        if (act) {
            cl[0] = fminf(e[0] / s2x, 0.6f); cl[1] = fminf(e[1] / s2x, 0.6f);
            cl[2] = fminf(e[2] / s2x, 0.6f); cl[3] = fminf(e[3] / s2x, 0.6f);
            cs = (cl[0] + cl[1]) + (cl[2] + cl[3]);
        }
        const float rsum = block_sum_f(cs, redf, tid);
        int k[4] = {0, 0, 0, 0};
        int kls = 0;
        if (act) {
            k[0] = (int)rintf((cl[0] / rsum) * 10.0f);
            k[1] = (int)rintf((cl[1] / rsum) * 10.0f);
            k[2] = (int)rintf((cl[2] / rsum) * 10.0f);
            k[3] = (int)rintf((cl[3] / rsum) * 10.0f);
            kls = k[0] + k[1] + k[2] + k[3];
        }
        const int K = block_sum_i(kls, redi, tid);
        if (K == 0) {
            const float th = uu * T[NCLS - 1];
            int cnt = 0;
            if (act) {
                float4 tv = reinterpret_cast<const float4*>(T)[tid];
                cnt = (tv.x < th) + (tv.y < th) + (tv.z < th) + (tv.w < th);
            }
            idx = block_sum_i(cnt, redi, tid);
        } else {
            if (act) {
                kbuf[4 * tid + 0] = (unsigned char)k[0];
                kbuf[4 * tid + 1] = (unsigned char)k[1];
                kbuf[4 * tid + 2] = (unsigned char)k[2];
                kbuf[4 * tid + 3] = (unsigned char)k[3];
            }
            __syncthreads();
            if (tid == 0) {
                const double tab[11] = {0.0, 0.1, 0.2, 0.3, 0.4, 0.5,
                                        0.6, 0.7, 0.8, 0.9, 1.0};
                double c = 0.0;
                for (int i = 0; i < NCLS; ++i) c += tab[kbuf[i]];
                const double th = (double)uu * c;
                c = 0.0;
                int cnt = 0;
                for (int i = 0; i < NCLS; ++i) {
                    c += tab[kbuf[i]];
                    cnt += (c < th) ? 1 : 0;
                }
                i_bcast = cnt;
            }
            __syncthreads();
            idx = i_bcast;
        }
    }

    // epilogue: log(one_hot*(1-EPS) + EPS/C) — identical expressions to R3
    const float V0 = logf(1e-7f);             // EPS/C
    const float V1 = logf(0.9999f + 1e-7f);   // (1-EPS) + EPS/C
    if (act) {
        float4 ov = {V0, V0, V0, V0};
        const int base = tid * 4;
        if (idx >= base && idx < base + 4)
            (&ov.x)[idx - base] = V1;
        reinterpret_cast<float4*>(out + (size_t)row * NCLS)[tid] = ov;
    }
}

extern "C" void kernel_launch(void* const* d_in, const int* in_sizes, int n_in,
                              void* d_out, int out_size, void* d_ws, size_t ws_size,
                              hipStream_t stream) {
    const float* logits = (const float*)d_in[0];
    const float* noise  = (const float*)d_in[1];
    const float* u      = (const float*)d_in[2];
    float* out = (float*)d_out;
    float* T   = (float*)d_ws;           // 4000 B table; ws is ample

    const int batch = in_sizes[2];       // 32768 rows (u is [B,1])

    hipLaunchKernelGGL(init_tab, dim3((NCLS + TPB - 1) / TPB), dim3(TPB), 0, stream, T);
    hipLaunchKernelGGL(defence_kernel, dim3(batch), dim3(TPB), 0, stream,
                       logits, noise, u, T, out);
}

// Round 5
// 88.886 us; speedup vs baseline: 1.7549x; 1.1110x over previous
//
#include <hip/hip_runtime.h>
#include <math.h>

#define NCLS 1000
#define NF4  250     // float4s per row
#define TPB  256
#define WPB  4       // waves (rows) per block

#if __has_builtin(__builtin_amdgcn_exp2f)
__device__ __forceinline__ float fast_exp2(float x) { return __builtin_amdgcn_exp2f(x); }
#else
__device__ __forceinline__ float fast_exp2(float x) { return exp2f(x); }
#endif

// ---------------------------------------------------------------------------
// cum[i] for the uniform row per jax.lax.associative_scan (tree) order.
// Verified bit-exact in R3/R4 (absmax == 0.0).
// ---------------------------------------------------------------------------
__device__ __forceinline__ float scan_val(int k) {
    const unsigned xb = __float_as_uint(0.001f);
    const int hb = 31 - __clz(k);
    float acc = __uint_as_float(xb + ((unsigned)hb << 23));  // x * 2^hb, exact
    #pragma unroll 1
    for (int l = hb - 1; l >= 0; --l) {
        if (k & (1u << l)) {
            const float t = __uint_as_float(xb + ((unsigned)l << 23)); // x*2^l
            acc += t;
            asm volatile("" : "+v"(acc));
        }
    }
    return acc;
}

__global__ void init_tab(float* __restrict__ T) {
    const int i = blockIdx.x * blockDim.x + threadIdx.x;
    if (i < NCLS) T[i] = scan_val(i + 1);
}

// ---------------------------------------------------------------------------
// Wave-level (64-lane) reductions — pure register butterflies, no barriers.
// ---------------------------------------------------------------------------
__device__ __forceinline__ float wave_max(float v) {
    #pragma unroll
    for (int o = 32; o; o >>= 1) v = fmaxf(v, __shfl_xor(v, o));
    return v;
}
__device__ __forceinline__ float wave_sum(float v) {
    #pragma unroll
    for (int o = 32; o; o >>= 1) v += __shfl_xor(v, o);
    return v;
}
__device__ __forceinline__ int wave_sumi(int v) {
    #pragma unroll
    for (int o = 32; o; o >>= 1) v += __shfl_xor(v, o);
    return v;
}

// ---------------------------------------------------------------------------
// One WAVE per row. No __syncthreads anywhere.
// ---------------------------------------------------------------------------
__global__ __launch_bounds__(TPB) void defence_kernel(
    const float* __restrict__ logits,
    const float* __restrict__ noise,
    const float* __restrict__ u,
    const float* __restrict__ T,
    float* __restrict__ out,
    int batch)
{
    const int lane = threadIdx.x & 63;
    const int wid  = threadIdx.x >> 6;
    const int row  = blockIdx.x * WPB + wid;
    if (row >= batch) return;                    // wave-uniform

    __shared__ unsigned char kbuf[WPB][NCLS];    // cold path only

    const float4* lg4 = reinterpret_cast<const float4*>(logits + (size_t)row * NCLS);
    const float4* nz4 = reinterpret_cast<const float4*>(noise  + (size_t)row * NCLS);
    const float4* T4  = reinterpret_cast<const float4*>(T);

    const float NEG = -INFINITY;
    float4 lv[4];
    #pragma unroll
    for (int t = 0; t < 4; ++t) {
        const int j = lane + 64 * t;
        lv[t] = (j < NF4) ? lg4[j] : make_float4(NEG, NEG, NEG, NEG);
    }

    // ---- fast path: only has to decide K==0 (margin ~2x) + compute sd ----
    // pass A: unbiased exp2(l*K6); values tiny, no overflow possible.
    const float K6 = 0.2404491734814939f;        // log2(e)/6
    float m1l = NEG, s1l = 0.f;
    #pragma unroll
    for (int t = 0; t < 4; ++t) {
        m1l = fmaxf(m1l, fmaxf(fmaxf(lv[t].x, lv[t].y), fmaxf(lv[t].z, lv[t].w)));
        s1l += (fast_exp2(lv[t].x * K6) + fast_exp2(lv[t].y * K6))
             + (fast_exp2(lv[t].z * K6) + fast_exp2(lv[t].w * K6));
    }
    const float m1 = wave_max(m1l);              // independent chains — interleave
    const float s1 = wave_sum(s1l);
    const float mc = fast_exp2(m1 * K6) / s1;    // max softmax prob (approx)
    const float sd = fmaf(0.6f, mc * mc, 0.3f);

    // pass B: ny = l/6 + noise*sd; unbiased exp2(ny*L2E).
    const float L2E = 1.4426950408889634f;
    float4 nv[4];
    #pragma unroll
    for (int t = 0; t < 4; ++t) {
        const int j = lane + 64 * t;
        nv[t] = (j < NF4) ? nz4[j] : make_float4(0.f, 0.f, 0.f, 0.f);
    }
    float m2l = NEG, s2l = 0.f;
    #pragma unroll
    for (int t = 0; t < 4; ++t) {
        const float y0 = fmaf(nv[t].x, sd, lv[t].x * (1.0f / 6.0f));
        const float y1 = fmaf(nv[t].y, sd, lv[t].y * (1.0f / 6.0f));
        const float y2 = fmaf(nv[t].z, sd, lv[t].z * (1.0f / 6.0f));
        const float y3 = fmaf(nv[t].w, sd, lv[t].w * (1.0f / 6.0f));
        m2l = fmaxf(m2l, fmaxf(fmaxf(y0, y1), fmaxf(y2, y3)));
        s2l += (fast_exp2(y0 * L2E) + fast_exp2(y1 * L2E))
             + (fast_exp2(y2 * L2E) + fast_exp2(y3 * L2E));
    }
    const float m2  = wave_max(m2l);
    const float s2  = wave_sum(s2l);
    const float e2m = fast_exp2(m2 * L2E);       // overflow -> inf -> exact path

    const float uu = u[row];
    int idx;
    // K==0 <=> max renorm prob <= 0.05; require maxp_approx < 1/22 = 0.0455.
    // Data margin: maxp ~ 0.006-0.026. Boundary/overflow rows -> exact path.
    if (s2 > 22.0f * e2m) {
        const float th = uu * T[NCLS - 1];       // bit-identical sampling
        int cnt = 0;
        #pragma unroll
        for (int t = 0; t < 4; ++t) {
            const int j = lane + 64 * t;
            if (j < NF4) {
                float4 tv = T4[j];
                cnt += (tv.x < th) + (tv.y < th) + (tv.z < th) + (tv.w < th);
            }
        }
        idx = wave_sumi(cnt);
    } else {
        // ---- exact reference-semantics path (wave-uniform; cold) ----
        const float m1x = wave_max(m1l) / 6.0f;  // max(l)/6 == max(l/6): div monotone
        float se1x = 0.f;
        #pragma unroll
        for (int t = 0; t < 4; ++t) {
            se1x += expf(lv[t].x / 6.0f - m1x) + expf(lv[t].y / 6.0f - m1x)
                  + expf(lv[t].z / 6.0f - m1x) + expf(lv[t].w / 6.0f - m1x);
        }
        const float s1x = wave_sum(se1x);
        const float mcx = 1.0f / s1x;
        const float sdx = 0.3f + 0.6f * (mcx * mcx);

        float m2xl = NEG;
        #pragma unroll
        for (int t = 0; t < 4; ++t) {
            const float y0 = lv[t].x / 6.0f + nv[t].x * sdx;
            const float y1 = lv[t].y / 6.0f + nv[t].y * sdx;
            const float y2 = lv[t].z / 6.0f + nv[t].z * sdx;
            const float y3 = lv[t].w / 6.0f + nv[t].w * sdx;
            m2xl = fmaxf(m2xl, fmaxf(fmaxf(y0, y1), fmaxf(y2, y3)));
        }
        const float m2x = wave_max(m2xl);
        float se2x = 0.f;
        #pragma unroll
        for (int t = 0; t < 4; ++t) {
            se2x += expf(lv[t].x / 6.0f + nv[t].x * sdx - m2x)
                  + expf(lv[t].y / 6.0f + nv[t].y * sdx - m2x)
                  + expf(lv[t].z / 6.0f + nv[t].z * sdx - m2x)
                  + expf(lv[t].w / 6.0f + nv[t].w * sdx - m2x);
        }
        const float s2x = wave_sum(se2x);
        float csl = 0.f;
        #pragma unroll
        for (int t = 0; t < 4; ++t) {
            csl += fminf(expf(lv[t].x / 6.0f + nv[t].x * sdx - m2x) / s2x, 0.6f)
                 + fminf(expf(lv[t].y / 6.0f + nv[t].y * sdx - m2x) / s2x, 0.6f)
                 + fminf(expf(lv[t].z / 6.0f + nv[t].z * sdx - m2x) / s2x, 0.6f)
                 + fminf(expf(lv[t].w / 6.0f + nv[t].w * sdx - m2x) / s2x, 0.6f);
        }
        const float rsum = wave_sum(csl);
        int kls = 0;
        #pragma unroll
        for (int t = 0; t < 4; ++t) {
            const int j = lane + 64 * t;
            if (j < NF4) {
                const float yv[4] = {
                    lv[t].x / 6.0f + nv[t].x * sdx, lv[t].y / 6.0f + nv[t].y * sdx,
                    lv[t].z / 6.0f + nv[t].z * sdx, lv[t].w / 6.0f + nv[t].w * sdx };
                #pragma unroll
                for (int c = 0; c < 4; ++c) {
                    const float cl = fminf(expf(yv[c] - m2x) / s2x, 0.6f);
                    const int kk = (int)rintf((cl / rsum) * 10.0f);
                    kbuf[wid][4 * j + c] = (unsigned char)kk;
                    kls += kk;
                }
            }
        }
        const int K = wave_sumi(kls);
        if (K == 0) {
            const float th = uu * T[NCLS - 1];
            int cnt = 0;
            #pragma unroll
            for (int t = 0; t < 4; ++t) {
                const int j = lane + 64 * t;
                if (j < NF4) {
                    float4 tv = T4[j];
                    cnt += (tv.x < th) + (tv.y < th) + (tv.z < th) + (tv.w < th);
                }
            }
            idx = wave_sumi(cnt);
        } else {
            asm volatile("s_waitcnt lgkmcnt(0)" ::: "memory");
            __builtin_amdgcn_wave_barrier();
            int cnt = 0;
            if (lane == 0) {
                const double tab[11] = {0.0, 0.1, 0.2, 0.3, 0.4, 0.5,
                                        0.6, 0.7, 0.8, 0.9, 1.0};
                double c = 0.0;
                for (int i = 0; i < NCLS; ++i) c += tab[kbuf[wid][i]];
                const double th = (double)uu * c;
                c = 0.0;
                for (int i = 0; i < NCLS; ++i) {
                    c += tab[kbuf[wid][i]];
                    cnt += (c < th) ? 1 : 0;
                }
            }
            idx = __shfl(cnt, 0);
        }
    }

    // epilogue: log(one_hot*(1-EPS) + EPS/C) — identical expressions to R3/R4
    const float V0 = logf(1e-7f);
    const float V1 = logf(0.9999f + 1e-7f);
    float4* o4 = reinterpret_cast<float4*>(out + (size_t)row * NCLS);
    #pragma unroll
    for (int t = 0; t < 4; ++t) {
        const int j = lane + 64 * t;
        if (j < NF4) {
            float4 ov = {V0, V0, V0, V0};
            const int base = 4 * j;
            if (idx >= base && idx < base + 4)
                (&ov.x)[idx - base] = V1;
            o4[j] = ov;
        }
    }
}

extern "C" void kernel_launch(void* const* d_in, const int* in_sizes, int n_in,
                              void* d_out, int out_size, void* d_ws, size_t ws_size,
                              hipStream_t stream) {
    const float* logits = (const float*)d_in[0];
    const float* noise  = (const float*)d_in[1];
    const float* u      = (const float*)d_in[2];
    float* out = (float*)d_out;
    float* T   = (float*)d_ws;           // 4000 B table

    const int batch = in_sizes[2];       // 32768 rows (u is [B,1])
    const int blocks = (batch + WPB - 1) / WPB;

    hipLaunchKernelGGL(init_tab, dim3((NCLS + TPB - 1) / TPB), dim3(TPB), 0, stream, T);
    hipLaunchKernelGGL(defence_kernel, dim3(blocks), dim3(TPB), 0, stream,
                       logits, noise, u, T, out, batch);
}